// Round 3
// baseline (160.392 us; speedup 1.0000x reference)
//
#include <hip/hip_runtime.h>

#define NPIX 6400

typedef float f4 __attribute__((ext_vector_type(4)));
typedef float f16v __attribute__((ext_vector_type(16)));
typedef short bf16x8 __attribute__((ext_vector_type(8)));
typedef unsigned int u4 __attribute__((ext_vector_type(4)));
typedef unsigned short u16;
typedef unsigned int u32;

__device__ __forceinline__ u16 f2bf(float f){
  union { float f; u32 u; } v; v.f = f;
  u32 r = v.u + 0x7fffu + ((v.u >> 16) & 1u);
  return (u16)(r >> 16);
}

__device__ __forceinline__ float exp2_hw(float x){ return __builtin_amdgcn_exp2f(x); }

// ---------------- K1: projection GEMMs (fp32) + BN partial stats ----------------
__global__ __launch_bounds__(256, 1) void k_proj(
    const float* __restrict__ xq, const float* __restrict__ xk, const float* __restrict__ xv,
    const float* __restrict__ wq, const float* __restrict__ bq,
    const float* __restrict__ wk, const float* __restrict__ bk,
    const float* __restrict__ wv, const float* __restrict__ bv,
    float* __restrict__ Y, float* __restrict__ psum, float* __restrict__ psq)
{
  __shared__ __align__(16) float wT[64][132];
  __shared__ __align__(16) float xt[64][68];
  __shared__ __align__(16) float red[2][8][128];
  const int bid = blockIdx.x;
  const int proj = bid / 100, pt = bid % 100;
  const float* x = (proj == 0) ? xq : ((proj == 1) ? xk : xv);
  const float* w = (proj == 0) ? wq : ((proj == 1) ? wk : wv);
  const float* b = (proj == 0) ? bq : ((proj == 1) ? bk : bv);
  const int t = threadIdx.x;
  const int o0 = (t & 31) * 4, p0 = (t >> 5) * 8;
  float acc[4][8];
  #pragma unroll
  for (int i = 0; i < 4; ++i)
    #pragma unroll
    for (int j = 0; j < 8; ++j) acc[i][j] = 0.f;
  for (int cc = 0; cc < 2; ++cc){
    __syncthreads();
    for (int idx = t; idx < 2048; idx += 256){
      int o = idx >> 4, c4 = (idx & 15) * 4;
      f4 wv4 = *(const f4*)&w[o * 128 + cc * 64 + c4];
      wT[c4 + 0][o] = wv4[0]; wT[c4 + 1][o] = wv4[1];
      wT[c4 + 2][o] = wv4[2]; wT[c4 + 3][o] = wv4[3];
    }
    for (int idx = t; idx < 1024; idx += 256){
      int c = idx >> 4, p4 = (idx & 15) * 4;
      *(f4*)&xt[c][p4] = *(const f4*)&x[(cc * 64 + c) * NPIX + pt * 64 + p4];
    }
    __syncthreads();
    for (int c = 0; c < 64; ++c){
      f4 w4 = *(const f4*)&wT[c][o0];
      f4 x0 = *(const f4*)&xt[c][p0];
      f4 x1 = *(const f4*)&xt[c][p0 + 4];
      #pragma unroll
      for (int i = 0; i < 4; ++i){
        float wi = w4[i];
        #pragma unroll
        for (int j = 0; j < 4; ++j){ acc[i][j] += wi * x0[j]; acc[i][4 + j] += wi * x1[j]; }
      }
    }
  }
  f4 b4 = *(const f4*)&b[o0];
  #pragma unroll
  for (int i = 0; i < 4; ++i)
    #pragma unroll
    for (int j = 0; j < 8; ++j) acc[i][j] += b4[i];
  #pragma unroll
  for (int i = 0; i < 4; ++i){
    float s = 0.f, q = 0.f;
    #pragma unroll
    for (int j = 0; j < 8; ++j){ s += acc[i][j]; q += acc[i][j] * acc[i][j]; }
    red[0][t >> 5][o0 + i] = s;
    red[1][t >> 5][o0 + i] = q;
  }
  __syncthreads();
  if (t < 128){
    float s = 0.f, q = 0.f;
    #pragma unroll
    for (int g = 0; g < 8; ++g){ s += red[0][g][t]; q += red[1][g][t]; }
    psum[(proj * 100 + pt) * 128 + t] = s;
    psq [(proj * 100 + pt) * 128 + t] = q;
  }
  float* Yb = Y + (size_t)proj * NPIX * 128;
  if (proj < 2){
    #pragma unroll
    for (int j = 0; j < 8; ++j){
      f4 v; v[0] = acc[0][j]; v[1] = acc[1][j]; v[2] = acc[2][j]; v[3] = acc[3][j];
      *(f4*)&Yb[(size_t)(pt * 64 + p0 + j) * 128 + o0] = v;
    }
  } else {
    #pragma unroll
    for (int i = 0; i < 4; ++i){
      f4 v0, v1;
      #pragma unroll
      for (int j = 0; j < 4; ++j){ v0[j] = acc[i][j]; v1[j] = acc[i][4 + j]; }
      float* r = &Yb[(size_t)(o0 + i) * NPIX + pt * 64 + p0];
      *(f4*)r = v0; *(f4*)(r + 4) = v1;
    }
  }
}

// ---------------- K2: finalize BN affine + normalize+ReLU+bf16 cast ----------------
__global__ __launch_bounds__(256, 1) void k_norm(
    const float* __restrict__ Y, const float* __restrict__ psum, const float* __restrict__ psq,
    const float* __restrict__ gq, const float* __restrict__ beq,
    const float* __restrict__ gk, const float* __restrict__ bek,
    const float* __restrict__ gv, const float* __restrict__ bev,
    u16* __restrict__ q2, u16* __restrict__ k2, u16* __restrict__ v2t,
    float* __restrict__ rowsumq)
{
  __shared__ float sc[128], sh[128];
  const int bid = blockIdx.x, t = threadIdx.x;
  const int proj = bid / 100, pt = bid % 100;
  if (t < 128){
    float s = 0.f, q = 0.f;
    for (int i = 0; i < 100; ++i){
      s += psum[(proj * 100 + i) * 128 + t];
      q += psq [(proj * 100 + i) * 128 + t];
    }
    float mean = s * (1.f / NPIX);
    float var  = q * (1.f / NPIX) - mean * mean;
    const float* g  = (proj == 0) ? gq : ((proj == 1) ? gk : gv);
    const float* be = (proj == 0) ? beq : ((proj == 1) ? bek : bev);
    float scale = g[t] * rsqrtf(var + 1e-5f);
    sc[t] = scale; sh[t] = be[t] - mean * scale;
  }
  __syncthreads();
  const float* Yb = Y + (size_t)proj * NPIX * 128;
  if (proj < 2){
    int row = pt * 64 + (t >> 2), o0 = (t & 3) * 32;
    float rs = 0.f;
    u32 pkd[16];
    #pragma unroll
    for (int u = 0; u < 8; ++u){
      f4 y = *(const f4*)&Yb[(size_t)row * 128 + o0 + u * 4];
      #pragma unroll
      for (int e = 0; e < 4; ++e){
        int o = o0 + u * 4 + e;
        float v = fmaxf(y[e] * sc[o] + sh[o], 0.f);
        rs += v; y[e] = v;
      }
      pkd[u * 2]     = (u32)f2bf(y[0]) | ((u32)f2bf(y[1]) << 16);
      pkd[u * 2 + 1] = (u32)f2bf(y[2]) | ((u32)f2bf(y[3]) << 16);
    }
    u16* dst = (proj == 0) ? q2 : k2;
    u4* dp = (u4*)(dst + (size_t)row * 128 + o0);
    #pragma unroll
    for (int u = 0; u < 4; ++u){
      u4 v; v[0] = pkd[u*4]; v[1] = pkd[u*4+1]; v[2] = pkd[u*4+2]; v[3] = pkd[u*4+3];
      dp[u] = v;
    }
    if (proj == 0){
      rs += __shfl_xor(rs, 1);
      rs += __shfl_xor(rs, 2);
      if ((t & 3) == 0) rowsumq[row] = rs;
    }
  } else {
    int o = t >> 1, pc = pt * 64 + (t & 1) * 32;
    float scale = sc[o], shift = sh[o];
    u32 pkd[16];
    #pragma unroll
    for (int u = 0; u < 8; ++u){
      f4 y = *(const f4*)&Yb[(size_t)o * NPIX + pc + u * 4];
      #pragma unroll
      for (int e = 0; e < 4; ++e) y[e] = fmaxf(y[e] * scale + shift, 0.f);
      pkd[u * 2]     = (u32)f2bf(y[0]) | ((u32)f2bf(y[1]) << 16);
      pkd[u * 2 + 1] = (u32)f2bf(y[2]) | ((u32)f2bf(y[3]) << 16);
    }
    u4* dp = (u4*)(v2t + (size_t)o * NPIX + pc);
    #pragma unroll
    for (int u = 0; u < 4; ++u){
      u4 v; v[0] = pkd[u*4]; v[1] = pkd[u*4+1]; v[2] = pkd[u*4+2]; v[3] = pkd[u*4+3];
      dp[u] = v;
    }
  }
}

// ---------------- K3: flash attention (log2-domain softmax, defer-max) ----------------
// grid 50*js blocks, 4 waves x 32 q-rows. jsi split gets nkt 64-key tiles.
__global__ __launch_bounds__(256, 1) void k_flash(
    const u16* __restrict__ q2, const u16* __restrict__ k2, const u16* __restrict__ v2t,
    const float* __restrict__ rowsumq, const float* __restrict__ pos,
    float* __restrict__ Opart, float* __restrict__ Mout, float* __restrict__ Lout,
    int js, int ktbase, int ktrem)
{
  __shared__ __align__(16) u16 Kt[64 * 128];
  __shared__ __align__(16) u16 Vt[128 * 64];
  __shared__ __align__(16) float posT[64];
  const int bid = blockIdx.x;
  const int qb = bid / js, jsi = bid % js;
  const int kt0 = jsi * ktbase + min(jsi, ktrem);
  const int nkt = ktbase + (jsi < ktrem ? 1 : 0);
  const int tid = threadIdx.x;
  const int ln = tid & 63, wid = tid >> 6;
  const int lo = ln & 31, hi = ln >> 5;
  const int qrow = qb * 128 + wid * 32 + lo;
  bf16x8 qf[8];
  const u16* qp = q2 + (size_t)qrow * 128 + hi * 8;
  #pragma unroll
  for (int kk = 0; kk < 8; ++kk) qf[kk] = *(const bf16x8*)(qp + kk * 16);
  const float rsq_l2 = rowsumq[qrow] * 1.4426950408889634f;
  f16v accO[4];
  #pragma unroll
  for (int c = 0; c < 4; ++c)
    #pragma unroll
    for (int r = 0; r < 16; ++r) accO[c][r] = 0.f;
  float m = -1e30f, l = 0.f;
  const float qs_l2 = 0.12751700f; // 1/sqrt(128)/ln(2)
  #pragma unroll 1
  for (int kt = 0; kt < nkt; ++kt){
    const int j0 = (kt0 + kt) * 64;
    __syncthreads();
    #pragma unroll
    for (int it = 0; it < 4; ++it){
      int idx = tid + it * 256;
      int j = idx >> 4, c8 = idx & 15;
      bf16x8 val = *(const bf16x8*)(k2 + (size_t)(j0 + j) * 128 + c8 * 8);
      *(bf16x8*)((char*)Kt + j * 256 + ((c8 * 16) ^ ((j & 15) << 4))) = val;
    }
    #pragma unroll
    for (int it = 0; it < 4; ++it){
      int idx = tid + it * 256;
      int d = idx >> 3, c8 = idx & 7;
      bf16x8 val = *(const bf16x8*)(v2t + (size_t)d * NPIX + j0 + c8 * 8);
      *(bf16x8*)((char*)Vt + d * 128 + ((c8 * 16) ^ ((d & 7) << 4))) = val;
    }
    if (tid < 64) posT[tid] = pos[j0 + tid];
    __syncthreads();
    f16v accS0, accS1;
    #pragma unroll
    for (int r = 0; r < 16; ++r){ accS0[r] = 0.f; accS1[r] = 0.f; }
    {
      const char* kb0 = (const char*)Kt + lo * 256;
      const char* kb1 = (const char*)Kt + (32 + lo) * 256;
      const int sw = (lo & 15) << 4;
      #pragma unroll
      for (int kk = 0; kk < 8; ++kk){
        int bo = (kk * 32 + hi * 16) ^ sw;
        bf16x8 kf0 = *(const bf16x8*)(kb0 + bo);
        bf16x8 kf1 = *(const bf16x8*)(kb1 + bo);
        accS0 = __builtin_amdgcn_mfma_f32_32x32x16_bf16(kf0, qf[kk], accS0, 0, 0, 0);
        accS1 = __builtin_amdgcn_mfma_f32_32x32x16_bf16(kf1, qf[kk], accS1, 0, 0, 0);
      }
    }
    float pv[32];
    float mx = -1e30f;
    #pragma unroll
    for (int jsb = 0; jsb < 2; ++jsb){
      #pragma unroll
      for (int g = 0; g < 4; ++g){
        f4 p4 = *(const f4*)&posT[jsb * 32 + g * 8 + hi * 4];
        #pragma unroll
        for (int e = 0; e < 4; ++e){
          float sv = (jsb ? accS1[g * 4 + e] : accS0[g * 4 + e]) * qs_l2 + rsq_l2 * p4[e];
          pv[jsb * 16 + g * 4 + e] = sv;
          mx = fmaxf(mx, sv);
        }
      }
    }
    mx = fmaxf(mx, __shfl_xor(mx, 32));
    if (!__all(mx - m <= 11.5f)){
      float mnew = fmaxf(m, mx);
      float corr = exp2_hw(m - mnew);
      m = mnew;
      l *= corr;
      #pragma unroll
      for (int c = 0; c < 4; ++c)
        #pragma unroll
        for (int r = 0; r < 16; ++r) accO[c][r] *= corr;
    }
    float ls = 0.f;
    u32 pk[16], pks[16];
    #pragma unroll
    for (int i = 0; i < 16; ++i){
      float e0 = exp2_hw(pv[2 * i]     - m);
      float e1 = exp2_hw(pv[2 * i + 1] - m);
      ls += e0 + e1;
      pk[i] = (u32)f2bf(e0) | ((u32)f2bf(e1) << 16);
    }
    ls += __shfl_xor(ls, 32);
    l += ls;
    #pragma unroll
    for (int i = 0; i < 16; ++i) pks[i] = __shfl_xor(pk[i], 32);
    #pragma unroll
    for (int w = 0; w < 4; ++w){
      const int b0 = (w >> 1) * 8 + (w & 1) * 4;
      union { bf16x8 v; u32 u[4]; } pf;
      pf.u[0] = hi ? pks[b0 + 2] : pk[b0];
      pf.u[1] = hi ? pks[b0 + 3] : pk[b0 + 1];
      pf.u[2] = hi ? pk[b0 + 2]  : pks[b0];
      pf.u[3] = hi ? pk[b0 + 3]  : pks[b0 + 1];
      #pragma unroll
      for (int c = 0; c < 4; ++c){
        int d = c * 32 + lo;
        bf16x8 vf = *(const bf16x8*)((const char*)Vt + d * 128 + ((w * 32 + hi * 16) ^ ((d & 7) << 4)));
        accO[c] = __builtin_amdgcn_mfma_f32_32x32x16_bf16(vf, pf.v, accO[c], 0, 0, 0);
      }
    }
  }
  if (hi == 0){
    Mout[jsi * NPIX + qrow] = m;
    Lout[jsi * NPIX + qrow] = l;
  }
  float* Ob = Opart + ((size_t)jsi * NPIX + qrow) * 128;
  #pragma unroll
  for (int c = 0; c < 4; ++c){
    #pragma unroll
    for (int g = 0; g < 4; ++g){
      f4 v;
      #pragma unroll
      for (int e = 0; e < 4; ++e) v[e] = accO[c][g * 4 + e];
      *(f4*)&Ob[c * 32 + g * 8 + hi * 4] = v;
    }
  }
}

// ---------------- K3b: combine splits -> Ocomb (overlays Opart[0]) ----------------
// grid 800 x 256: thread -> (p, 4 channels)
__global__ __launch_bounds__(256, 1) void k_comb(
    const float* __restrict__ Opart, const float* __restrict__ Mbuf, const float* __restrict__ Lbuf,
    float* __restrict__ Ocomb, int js)
{
  const int idx = blockIdx.x * 256 + threadIdx.x;
  const int p = idx >> 5, c4 = (idx & 31) * 4;
  float mmax = -1e30f;
  for (int s = 0; s < js; ++s) mmax = fmaxf(mmax, Mbuf[s * NPIX + p]);
  float den = 0.f;
  f4 acc = {0.f, 0.f, 0.f, 0.f};
  for (int s = 0; s < js; ++s){
    float w = exp2_hw(Mbuf[s * NPIX + p] - mmax);
    den += w * Lbuf[s * NPIX + p];
    f4 o = *(const f4*)&Opart[((size_t)s * NPIX + p) * 128 + c4];
    acc += o * w;
  }
  float inv = 1.f / den;
  *(f4*)&Ocomb[(size_t)p * 128 + c4] = acc * inv;
}

// ---------------- K4: Z = Ocomb@wo1^T + bo1 (bf16 MFMA) + BN2 partials ----------
__global__ __launch_bounds__(64, 1) void k_gemm1(
    const float* __restrict__ Ocomb,
    const float* __restrict__ wo1, const float* __restrict__ bo1,
    float* __restrict__ Z, float* __restrict__ p2s, float* __restrict__ p2q)
{
  const int ln = threadIdx.x, lo = ln & 31, hi = ln >> 5;
  const int p = blockIdx.x * 32 + lo;
  bf16x8 bfr[8];
  #pragma unroll
  for (int kk = 0; kk < 8; ++kk){
    const float* op = Ocomb + (size_t)p * 128 + kk * 16 + hi * 8;
    f4 a0 = *(const f4*)op;
    f4 a1 = *(const f4*)(op + 4);
    union { bf16x8 v; u16 s16[8]; } u;
    #pragma unroll
    for (int e = 0; e < 4; ++e){ u.s16[e] = f2bf(a0[e]); u.s16[4 + e] = f2bf(a1[e]); }
    bfr[kk] = u.v;
  }
  f16v acc[4];
  #pragma unroll
  for (int c = 0; c < 4; ++c)
    #pragma unroll
    for (int r = 0; r < 16; ++r) acc[c][r] = 0.f;
  #pragma unroll
  for (int c = 0; c < 4; ++c){
    int o2r = c * 32 + lo;
    #pragma unroll
    for (int kk = 0; kk < 8; ++kk){
      const float* wp = wo1 + (size_t)o2r * 128 + kk * 16 + hi * 8;
      f4 w0 = *(const f4*)wp;
      f4 w1 = *(const f4*)(wp + 4);
      union { bf16x8 v; u16 s16[8]; } u;
      #pragma unroll
      for (int e = 0; e < 4; ++e){ u.s16[e] = f2bf(w0[e]); u.s16[4 + e] = f2bf(w1[e]); }
      acc[c] = __builtin_amdgcn_mfma_f32_32x32x16_bf16(u.v, bfr[kk], acc[c], 0, 0, 0);
    }
  }
  #pragma unroll
  for (int c = 0; c < 4; ++c){
    #pragma unroll
    for (int g = 0; g < 4; ++g){
      int o2 = c * 32 + g * 8 + hi * 4;
      f4 b4 = *(const f4*)&bo1[o2];
      f4 zv;
      #pragma unroll
      for (int e = 0; e < 4; ++e) zv[e] = acc[c][g * 4 + e] + b4[e];
      *(f4*)&Z[(size_t)p * 128 + o2] = zv;
      #pragma unroll
      for (int e = 0; e < 4; ++e){
        float sv = zv[e], qv = zv[e] * zv[e];
        #pragma unroll
        for (int msk = 1; msk < 32; msk <<= 1){ sv += __shfl_xor(sv, msk); qv += __shfl_xor(qv, msk); }
        if (lo == 0){
          p2s[blockIdx.x * 128 + o2 + e] = sv;
          p2q[blockIdx.x * 128 + o2 + e] = qv;
        }
      }
    }
  }
}

// ---------------- K5: finalize BN2 + H=relu(affine(Z)) + out = wo2@H + bo2 ----------
__global__ __launch_bounds__(64, 1) void k_gemm2(
    const float* __restrict__ Z, const float* __restrict__ p2s, const float* __restrict__ p2q,
    const float* __restrict__ go, const float* __restrict__ beo,
    const float* __restrict__ wo2, const float* __restrict__ bo2,
    float* __restrict__ out)
{
  __shared__ float sc2[128], sh2[128];
  const int ln = threadIdx.x, lo = ln & 31, hi = ln >> 5;
  for (int ch = ln; ch < 128; ch += 64){
    float s = 0.f, q = 0.f;
    for (int i = 0; i < 200; ++i){ s += p2s[i * 128 + ch]; q += p2q[i * 128 + ch]; }
    float mean = s * (1.f / NPIX);
    float var  = q * (1.f / NPIX) - mean * mean;
    float scale = go[ch] * rsqrtf(var + 1e-5f);
    sc2[ch] = scale; sh2[ch] = beo[ch] - mean * scale;
  }
  __syncthreads();
  const int p = blockIdx.x * 32 + lo;
  bf16x8 bfH[8];
  #pragma unroll
  for (int kk = 0; kk < 8; ++kk){
    int ob = kk * 16 + hi * 8;
    f4 z0 = *(const f4*)&Z[(size_t)p * 128 + ob];
    f4 z1 = *(const f4*)&Z[(size_t)p * 128 + ob + 4];
    f4 s0 = *(const f4*)&sc2[ob], s1 = *(const f4*)&sc2[ob + 4];
    f4 h0 = *(const f4*)&sh2[ob], h1 = *(const f4*)&sh2[ob + 4];
    union { bf16x8 v; u16 s16[8]; } u;
    #pragma unroll
    for (int e = 0; e < 4; ++e){
      u.s16[e]     = f2bf(fmaxf(z0[e] * s0[e] + h0[e], 0.f));
      u.s16[4 + e] = f2bf(fmaxf(z1[e] * s1[e] + h1[e], 0.f));
    }
    bfH[kk] = u.v;
  }
  f16v acc[4];
  #pragma unroll
  for (int c = 0; c < 4; ++c)
    #pragma unroll
    for (int r = 0; r < 16; ++r) acc[c][r] = 0.f;
  #pragma unroll
  for (int c = 0; c < 4; ++c){
    int o3r = c * 32 + lo;
    #pragma unroll
    for (int kk = 0; kk < 8; ++kk){
      const float* wp = wo2 + (size_t)o3r * 128 + kk * 16 + hi * 8;
      f4 w0 = *(const f4*)wp;
      f4 w1 = *(const f4*)(wp + 4);
      union { bf16x8 v; u16 s16[8]; } u;
      #pragma unroll
      for (int e = 0; e < 4; ++e){ u.s16[e] = f2bf(w0[e]); u.s16[4 + e] = f2bf(w1[e]); }
      acc[c] = __builtin_amdgcn_mfma_f32_32x32x16_bf16(u.v, bfH[kk], acc[c], 0, 0, 0);
    }
  }
  #pragma unroll
  for (int c = 0; c < 4; ++c){
    #pragma unroll
    for (int g = 0; g < 4; ++g){
      int o3 = c * 32 + g * 8 + hi * 4;
      f4 b4 = *(const f4*)&bo2[o3];
      #pragma unroll
      for (int e = 0; e < 4; ++e)
        out[(size_t)(o3 + e) * NPIX + p] = acc[c][g * 4 + e] + b4[e];
    }
  }
}

extern "C" void kernel_launch(void* const* d_in, const int* in_sizes, int n_in,
                              void* d_out, int out_size, void* d_ws, size_t ws_size,
                              hipStream_t stream)
{
  const float* query = (const float*)d_in[0];
  const float* key_  = (const float*)d_in[1];
  const float* value = (const float*)d_in[2];
  const float* pos   = (const float*)d_in[3];
  const float* wq = (const float*)d_in[4];  const float* bq = (const float*)d_in[5];
  const float* gq = (const float*)d_in[6];  const float* betaq = (const float*)d_in[7];
  const float* wk = (const float*)d_in[8];  const float* bk = (const float*)d_in[9];
  const float* gk = (const float*)d_in[10]; const float* betak = (const float*)d_in[11];
  const float* wv = (const float*)d_in[12]; const float* bv = (const float*)d_in[13];
  const float* gv = (const float*)d_in[14]; const float* betav = (const float*)d_in[15];
  const float* wo1 = (const float*)d_in[16]; const float* bo1 = (const float*)d_in[17];
  const float* go  = (const float*)d_in[18]; const float* betao = (const float*)d_in[19];
  const float* wo2 = (const float*)d_in[20]; const float* bo2 = (const float*)d_in[21];

  // adaptive K-split count based on available workspace
  const size_t fixed = 8729600;          // q2,k2,v2t,rowsumq,psum,psq,Z,p2s,p2q
  auto need = [&](int j) -> size_t {
    size_t ml = (size_t)j * 51200;       // M + L
    size_t yy = (size_t)j * 3276800;     // Opart
    size_t ov = yy > 9830400 ? yy : (size_t)9830400;  // overlays Y
    return fixed + ml + ov;
  };
  int js = 5;
  if (ws_size >= need(10)) js = 10;
  if (ws_size >= need(15)) js = 15;
  if (ws_size >= need(20)) js = 20;
  const int ktbase = 100 / js, ktrem = 100 % js;

  char* W = (char*)d_ws;
  size_t off = 0;
  auto alloc = [&](size_t n){ char* p = W + off; off += n; return p; };
  u16*  q2      = (u16*)alloc(1638400);
  u16*  k2      = (u16*)alloc(1638400);
  u16*  v2t     = (u16*)alloc(1638400);
  float* rowsumq= (float*)alloc(25600);
  float* psum   = (float*)alloc(153600);
  float* psq    = (float*)alloc(153600);
  float* Z      = (float*)alloc(3276800);
  float* p2s    = (float*)alloc(102400);
  float* p2q    = (float*)alloc(102400);
  float* Mbuf   = (float*)alloc((size_t)js * 25600);
  float* Lbuf   = (float*)alloc((size_t)js * 25600);
  float* Y      = (float*)(W + off);   // Yq,Yk,Yv (dead after k_norm)
  float* Opart  = (float*)(W + off);   // overlays Y
  float* Ocomb  = Opart;               // overlays Opart[0] (1:1 elementwise, race-free)

  k_proj <<<dim3(300), dim3(256), 0, stream>>>(query, key_, value, wq, bq, wk, bk, wv, bv, Y, psum, psq);
  k_norm <<<dim3(300), dim3(256), 0, stream>>>(Y, psum, psq, gq, betaq, gk, betak, gv, betav, q2, k2, v2t, rowsumq);
  k_flash<<<dim3(50 * js), dim3(256), 0, stream>>>(q2, k2, v2t, rowsumq, pos, Opart, Mbuf, Lbuf, js, ktbase, ktrem);
  k_comb <<<dim3(800), dim3(256), 0, stream>>>(Opart, Mbuf, Lbuf, Ocomb, js);
  k_gemm1<<<dim3(200), dim3(64), 0, stream>>>(Ocomb, wo1, bo1, Z, p2s, p2q);
  k_gemm2<<<dim3(200), dim3(64), 0, stream>>>(Z, p2s, p2q, go, betao, wo2, bo2, (float*)d_out);
}

// Round 4
// 130.702 us; speedup vs baseline: 1.2272x; 1.2272x over previous
//
#include <hip/hip_runtime.h>

#define NPIX 6400

typedef float f4 __attribute__((ext_vector_type(4)));
typedef float f16v __attribute__((ext_vector_type(16)));
typedef short bf16x8 __attribute__((ext_vector_type(8)));
typedef unsigned int u4 __attribute__((ext_vector_type(4)));
typedef unsigned short u16;
typedef unsigned int u32;

__device__ __forceinline__ u16 f2bf(float f){
  union { float f; u32 u; } v; v.f = f;
  u32 r = v.u + 0x7fffu + ((v.u >> 16) & 1u);
  return (u16)(r >> 16);
}

__device__ __forceinline__ float exp2_hw(float x){ return __builtin_amdgcn_exp2f(x); }

// ---------------- K1: projection GEMMs (fp32) + BN partial stats ----------------
__global__ __launch_bounds__(256, 1) void k_proj(
    const float* __restrict__ xq, const float* __restrict__ xk, const float* __restrict__ xv,
    const float* __restrict__ wq, const float* __restrict__ bq,
    const float* __restrict__ wk, const float* __restrict__ bk,
    const float* __restrict__ wv, const float* __restrict__ bv,
    float* __restrict__ Y, float* __restrict__ psum, float* __restrict__ psq)
{
  __shared__ __align__(16) float wT[64][132];
  __shared__ __align__(16) float xt[64][68];
  __shared__ __align__(16) float red[2][8][128];
  const int bid = blockIdx.x;
  const int proj = bid / 100, pt = bid % 100;
  const float* x = (proj == 0) ? xq : ((proj == 1) ? xk : xv);
  const float* w = (proj == 0) ? wq : ((proj == 1) ? wk : wv);
  const float* b = (proj == 0) ? bq : ((proj == 1) ? bk : bv);
  const int t = threadIdx.x;
  const int o0 = (t & 31) * 4, p0 = (t >> 5) * 8;
  float acc[4][8];
  #pragma unroll
  for (int i = 0; i < 4; ++i)
    #pragma unroll
    for (int j = 0; j < 8; ++j) acc[i][j] = 0.f;
  for (int cc = 0; cc < 2; ++cc){
    __syncthreads();
    for (int idx = t; idx < 2048; idx += 256){
      int o = idx >> 4, c4 = (idx & 15) * 4;
      f4 wv4 = *(const f4*)&w[o * 128 + cc * 64 + c4];
      wT[c4 + 0][o] = wv4[0]; wT[c4 + 1][o] = wv4[1];
      wT[c4 + 2][o] = wv4[2]; wT[c4 + 3][o] = wv4[3];
    }
    for (int idx = t; idx < 1024; idx += 256){
      int c = idx >> 4, p4 = (idx & 15) * 4;
      *(f4*)&xt[c][p4] = *(const f4*)&x[(cc * 64 + c) * NPIX + pt * 64 + p4];
    }
    __syncthreads();
    for (int c = 0; c < 64; ++c){
      f4 w4 = *(const f4*)&wT[c][o0];
      f4 x0 = *(const f4*)&xt[c][p0];
      f4 x1 = *(const f4*)&xt[c][p0 + 4];
      #pragma unroll
      for (int i = 0; i < 4; ++i){
        float wi = w4[i];
        #pragma unroll
        for (int j = 0; j < 4; ++j){ acc[i][j] += wi * x0[j]; acc[i][4 + j] += wi * x1[j]; }
      }
    }
  }
  f4 b4 = *(const f4*)&b[o0];
  #pragma unroll
  for (int i = 0; i < 4; ++i)
    #pragma unroll
    for (int j = 0; j < 8; ++j) acc[i][j] += b4[i];
  #pragma unroll
  for (int i = 0; i < 4; ++i){
    float s = 0.f, q = 0.f;
    #pragma unroll
    for (int j = 0; j < 8; ++j){ s += acc[i][j]; q += acc[i][j] * acc[i][j]; }
    red[0][t >> 5][o0 + i] = s;
    red[1][t >> 5][o0 + i] = q;
  }
  __syncthreads();
  if (t < 128){
    float s = 0.f, q = 0.f;
    #pragma unroll
    for (int g = 0; g < 8; ++g){ s += red[0][g][t]; q += red[1][g][t]; }
    psum[(proj * 100 + pt) * 128 + t] = s;
    psq [(proj * 100 + pt) * 128 + t] = q;
  }
  float* Yb = Y + (size_t)proj * NPIX * 128;
  if (proj < 2){
    #pragma unroll
    for (int j = 0; j < 8; ++j){
      f4 v; v[0] = acc[0][j]; v[1] = acc[1][j]; v[2] = acc[2][j]; v[3] = acc[3][j];
      *(f4*)&Yb[(size_t)(pt * 64 + p0 + j) * 128 + o0] = v;
    }
  } else {
    #pragma unroll
    for (int i = 0; i < 4; ++i){
      f4 v0, v1;
      #pragma unroll
      for (int j = 0; j < 4; ++j){ v0[j] = acc[i][j]; v1[j] = acc[i][4 + j]; }
      float* r = &Yb[(size_t)(o0 + i) * NPIX + pt * 64 + p0];
      *(f4*)r = v0; *(f4*)(r + 4) = v1;
    }
  }
}

// ---------------- K2: finalize BN affine + normalize+ReLU+bf16 cast ----------------
__global__ __launch_bounds__(256, 1) void k_norm(
    const float* __restrict__ Y, const float* __restrict__ psum, const float* __restrict__ psq,
    const float* __restrict__ gq, const float* __restrict__ beq,
    const float* __restrict__ gk, const float* __restrict__ bek,
    const float* __restrict__ gv, const float* __restrict__ bev,
    u16* __restrict__ q2, u16* __restrict__ k2, u16* __restrict__ v2t,
    float* __restrict__ rowsumq)
{
  __shared__ float sc[128], sh[128];
  const int bid = blockIdx.x, t = threadIdx.x;
  const int proj = bid / 100, pt = bid % 100;
  if (t < 128){
    float s = 0.f, q = 0.f;
    for (int i = 0; i < 100; ++i){
      s += psum[(proj * 100 + i) * 128 + t];
      q += psq [(proj * 100 + i) * 128 + t];
    }
    float mean = s * (1.f / NPIX);
    float var  = q * (1.f / NPIX) - mean * mean;
    const float* g  = (proj == 0) ? gq : ((proj == 1) ? gk : gv);
    const float* be = (proj == 0) ? beq : ((proj == 1) ? bek : bev);
    float scale = g[t] * rsqrtf(var + 1e-5f);
    sc[t] = scale; sh[t] = be[t] - mean * scale;
  }
  __syncthreads();
  const float* Yb = Y + (size_t)proj * NPIX * 128;
  if (proj < 2){
    int row = pt * 64 + (t >> 2), o0 = (t & 3) * 32;
    float rs = 0.f;
    u32 pkd[16];
    #pragma unroll
    for (int u = 0; u < 8; ++u){
      f4 y = *(const f4*)&Yb[(size_t)row * 128 + o0 + u * 4];
      #pragma unroll
      for (int e = 0; e < 4; ++e){
        int o = o0 + u * 4 + e;
        float v = fmaxf(y[e] * sc[o] + sh[o], 0.f);
        rs += v; y[e] = v;
      }
      pkd[u * 2]     = (u32)f2bf(y[0]) | ((u32)f2bf(y[1]) << 16);
      pkd[u * 2 + 1] = (u32)f2bf(y[2]) | ((u32)f2bf(y[3]) << 16);
    }
    u16* dst = (proj == 0) ? q2 : k2;
    u4* dp = (u4*)(dst + (size_t)row * 128 + o0);
    #pragma unroll
    for (int u = 0; u < 4; ++u){
      u4 v; v[0] = pkd[u*4]; v[1] = pkd[u*4+1]; v[2] = pkd[u*4+2]; v[3] = pkd[u*4+3];
      dp[u] = v;
    }
    if (proj == 0){
      rs += __shfl_xor(rs, 1);
      rs += __shfl_xor(rs, 2);
      if ((t & 3) == 0) rowsumq[row] = rs;
    }
  } else {
    int o = t >> 1, pc = pt * 64 + (t & 1) * 32;
    float scale = sc[o], shift = sh[o];
    u32 pkd[16];
    #pragma unroll
    for (int u = 0; u < 8; ++u){
      f4 y = *(const f4*)&Yb[(size_t)o * NPIX + pc + u * 4];
      #pragma unroll
      for (int e = 0; e < 4; ++e) y[e] = fmaxf(y[e] * scale + shift, 0.f);
      pkd[u * 2]     = (u32)f2bf(y[0]) | ((u32)f2bf(y[1]) << 16);
      pkd[u * 2 + 1] = (u32)f2bf(y[2]) | ((u32)f2bf(y[3]) << 16);
    }
    u4* dp = (u4*)(v2t + (size_t)o * NPIX + pc);
    #pragma unroll
    for (int u = 0; u < 4; ++u){
      u4 v; v[0] = pkd[u*4]; v[1] = pkd[u*4+1]; v[2] = pkd[u*4+2]; v[3] = pkd[u*4+3];
      dp[u] = v;
    }
  }
}

// ---------------- K3: flash attention, 512 threads = 8 waves = 2 waves/SIMD ----------------
// grid 25*js blocks: qb = bid/js (256 q-rows), jsi = bid%js. Each wave owns 32 q-rows.
__global__ __launch_bounds__(512, 2) void k_flash(
    const u16* __restrict__ q2, const u16* __restrict__ k2, const u16* __restrict__ v2t,
    const float* __restrict__ rowsumq, const float* __restrict__ pos,
    float* __restrict__ Opart, float* __restrict__ Mout, float* __restrict__ Lout,
    int js, int ktbase, int ktrem)
{
  __shared__ __align__(16) u16 Kt[64 * 128];
  __shared__ __align__(16) u16 Vt[128 * 64];
  __shared__ __align__(16) float posT[64];
  const int bid = blockIdx.x;
  const int qb = bid / js, jsi = bid % js;
  const int kt0 = jsi * ktbase + min(jsi, ktrem);
  const int nkt = ktbase + (jsi < ktrem ? 1 : 0);
  const int tid = threadIdx.x;
  const int ln = tid & 63, wid = tid >> 6;
  const int lo = ln & 31, hi = ln >> 5;
  const int qrow = qb * 256 + wid * 32 + lo;
  bf16x8 qf[8];
  const u16* qp = q2 + (size_t)qrow * 128 + hi * 8;
  #pragma unroll
  for (int kk = 0; kk < 8; ++kk) qf[kk] = *(const bf16x8*)(qp + kk * 16);
  const float rsq_l2 = rowsumq[qrow] * 1.4426950408889634f;
  f16v accO[4];
  #pragma unroll
  for (int c = 0; c < 4; ++c)
    #pragma unroll
    for (int r = 0; r < 16; ++r) accO[c][r] = 0.f;
  float m = -1e30f, l = 0.f;
  const float qs_l2 = 0.12751700f; // 1/sqrt(128)/ln(2)
  #pragma unroll 1
  for (int kt = 0; kt < nkt; ++kt){
    const int j0 = (kt0 + kt) * 64;
    __syncthreads();
    #pragma unroll
    for (int it = 0; it < 2; ++it){
      int idx = tid + it * 512;
      int j = idx >> 4, c8 = idx & 15;
      bf16x8 val = *(const bf16x8*)(k2 + (size_t)(j0 + j) * 128 + c8 * 8);
      *(bf16x8*)((char*)Kt + j * 256 + ((c8 * 16) ^ ((j & 15) << 4))) = val;
    }
    #pragma unroll
    for (int it = 0; it < 2; ++it){
      int idx = tid + it * 512;
      int d = idx >> 3, c8 = idx & 7;
      bf16x8 val = *(const bf16x8*)(v2t + (size_t)d * NPIX + j0 + c8 * 8);
      *(bf16x8*)((char*)Vt + d * 128 + ((c8 * 16) ^ ((d & 7) << 4))) = val;
    }
    if (tid < 64) posT[tid] = pos[j0 + tid];
    __syncthreads();
    f16v accS0, accS1;
    #pragma unroll
    for (int r = 0; r < 16; ++r){ accS0[r] = 0.f; accS1[r] = 0.f; }
    {
      const char* kb0 = (const char*)Kt + lo * 256;
      const char* kb1 = (const char*)Kt + (32 + lo) * 256;
      const int sw = (lo & 15) << 4;
      #pragma unroll
      for (int kk = 0; kk < 8; ++kk){
        int bo = (kk * 32 + hi * 16) ^ sw;
        bf16x8 kf0 = *(const bf16x8*)(kb0 + bo);
        bf16x8 kf1 = *(const bf16x8*)(kb1 + bo);
        accS0 = __builtin_amdgcn_mfma_f32_32x32x16_bf16(kf0, qf[kk], accS0, 0, 0, 0);
        accS1 = __builtin_amdgcn_mfma_f32_32x32x16_bf16(kf1, qf[kk], accS1, 0, 0, 0);
      }
    }
    float pv[32];
    float mx = -1e30f;
    #pragma unroll
    for (int jsb = 0; jsb < 2; ++jsb){
      #pragma unroll
      for (int g = 0; g < 4; ++g){
        f4 p4 = *(const f4*)&posT[jsb * 32 + g * 8 + hi * 4];
        #pragma unroll
        for (int e = 0; e < 4; ++e){
          float sv = (jsb ? accS1[g * 4 + e] : accS0[g * 4 + e]) * qs_l2 + rsq_l2 * p4[e];
          pv[jsb * 16 + g * 4 + e] = sv;
          mx = fmaxf(mx, sv);
        }
      }
    }
    mx = fmaxf(mx, __shfl_xor(mx, 32));
    if (!__all(mx - m <= 11.5f)){
      float mnew = fmaxf(m, mx);
      float corr = exp2_hw(m - mnew);
      m = mnew;
      l *= corr;
      #pragma unroll
      for (int c = 0; c < 4; ++c)
        #pragma unroll
        for (int r = 0; r < 16; ++r) accO[c][r] *= corr;
    }
    float ls = 0.f;
    u32 pk[16], pks[16];
    #pragma unroll
    for (int i = 0; i < 16; ++i){
      float e0 = exp2_hw(pv[2 * i]     - m);
      float e1 = exp2_hw(pv[2 * i + 1] - m);
      ls += e0 + e1;
      pk[i] = (u32)f2bf(e0) | ((u32)f2bf(e1) << 16);
    }
    ls += __shfl_xor(ls, 32);
    l += ls;
    #pragma unroll
    for (int i = 0; i < 16; ++i) pks[i] = __shfl_xor(pk[i], 32);
    #pragma unroll
    for (int w = 0; w < 4; ++w){
      const int b0 = (w >> 1) * 8 + (w & 1) * 4;
      union { bf16x8 v; u32 u[4]; } pf;
      pf.u[0] = hi ? pks[b0 + 2] : pk[b0];
      pf.u[1] = hi ? pks[b0 + 3] : pk[b0 + 1];
      pf.u[2] = hi ? pk[b0 + 2]  : pks[b0];
      pf.u[3] = hi ? pk[b0 + 3]  : pks[b0 + 1];
      #pragma unroll
      for (int c = 0; c < 4; ++c){
        int d = c * 32 + lo;
        bf16x8 vf = *(const bf16x8*)((const char*)Vt + d * 128 + ((w * 32 + hi * 16) ^ ((d & 7) << 4)));
        accO[c] = __builtin_amdgcn_mfma_f32_32x32x16_bf16(vf, pf.v, accO[c], 0, 0, 0);
      }
    }
  }
  if (hi == 0){
    Mout[jsi * NPIX + qrow] = m;
    Lout[jsi * NPIX + qrow] = l;
  }
  float* Ob = Opart + ((size_t)jsi * NPIX + qrow) * 128;
  #pragma unroll
  for (int c = 0; c < 4; ++c){
    #pragma unroll
    for (int g = 0; g < 4; ++g){
      f4 v;
      #pragma unroll
      for (int e = 0; e < 4; ++e) v[e] = accO[c][g * 4 + e];
      *(f4*)&Ob[c * 32 + g * 8 + hi * 4] = v;
    }
  }
}

// ---------------- K3b: combine splits -> Ocomb (overlays Opart[0]) ----------------
__global__ __launch_bounds__(256, 1) void k_comb(
    const float* __restrict__ Opart, const float* __restrict__ Mbuf, const float* __restrict__ Lbuf,
    float* __restrict__ Ocomb, int js)
{
  const int idx = blockIdx.x * 256 + threadIdx.x;
  const int p = idx >> 5, c4 = (idx & 31) * 4;
  float mmax = -1e30f;
  for (int s = 0; s < js; ++s) mmax = fmaxf(mmax, Mbuf[s * NPIX + p]);
  float den = 0.f;
  f4 acc = {0.f, 0.f, 0.f, 0.f};
  for (int s = 0; s < js; ++s){
    float w = exp2_hw(Mbuf[s * NPIX + p] - mmax);
    den += w * Lbuf[s * NPIX + p];
    f4 o = *(const f4*)&Opart[((size_t)s * NPIX + p) * 128 + c4];
    acc += o * w;
  }
  float inv = 1.f / den;
  *(f4*)&Ocomb[(size_t)p * 128 + c4] = acc * inv;
}

// ---------------- K4: Z = Ocomb@wo1^T + bo1 (bf16 MFMA) + BN2 partials ----------
__global__ __launch_bounds__(64, 1) void k_gemm1(
    const float* __restrict__ Ocomb,
    const float* __restrict__ wo1, const float* __restrict__ bo1,
    float* __restrict__ Z, float* __restrict__ p2s, float* __restrict__ p2q)
{
  const int ln = threadIdx.x, lo = ln & 31, hi = ln >> 5;
  const int p = blockIdx.x * 32 + lo;
  bf16x8 bfr[8];
  #pragma unroll
  for (int kk = 0; kk < 8; ++kk){
    const float* op = Ocomb + (size_t)p * 128 + kk * 16 + hi * 8;
    f4 a0 = *(const f4*)op;
    f4 a1 = *(const f4*)(op + 4);
    union { bf16x8 v; u16 s16[8]; } u;
    #pragma unroll
    for (int e = 0; e < 4; ++e){ u.s16[e] = f2bf(a0[e]); u.s16[4 + e] = f2bf(a1[e]); }
    bfr[kk] = u.v;
  }
  f16v acc[4];
  #pragma unroll
  for (int c = 0; c < 4; ++c)
    #pragma unroll
    for (int r = 0; r < 16; ++r) acc[c][r] = 0.f;
  #pragma unroll
  for (int c = 0; c < 4; ++c){
    int o2r = c * 32 + lo;
    #pragma unroll
    for (int kk = 0; kk < 8; ++kk){
      const float* wp = wo1 + (size_t)o2r * 128 + kk * 16 + hi * 8;
      f4 w0 = *(const f4*)wp;
      f4 w1 = *(const f4*)(wp + 4);
      union { bf16x8 v; u16 s16[8]; } u;
      #pragma unroll
      for (int e = 0; e < 4; ++e){ u.s16[e] = f2bf(w0[e]); u.s16[4 + e] = f2bf(w1[e]); }
      acc[c] = __builtin_amdgcn_mfma_f32_32x32x16_bf16(u.v, bfr[kk], acc[c], 0, 0, 0);
    }
  }
  #pragma unroll
  for (int c = 0; c < 4; ++c){
    #pragma unroll
    for (int g = 0; g < 4; ++g){
      int o2 = c * 32 + g * 8 + hi * 4;
      f4 b4 = *(const f4*)&bo1[o2];
      f4 zv;
      #pragma unroll
      for (int e = 0; e < 4; ++e) zv[e] = acc[c][g * 4 + e] + b4[e];
      *(f4*)&Z[(size_t)p * 128 + o2] = zv;
      #pragma unroll
      for (int e = 0; e < 4; ++e){
        float sv = zv[e], qv = zv[e] * zv[e];
        #pragma unroll
        for (int msk = 1; msk < 32; msk <<= 1){ sv += __shfl_xor(sv, msk); qv += __shfl_xor(qv, msk); }
        if (lo == 0){
          p2s[blockIdx.x * 128 + o2 + e] = sv;
          p2q[blockIdx.x * 128 + o2 + e] = qv;
        }
      }
    }
  }
}

// ---------------- K5: finalize BN2 + H=relu(affine(Z)) + out = wo2@H + bo2 ----------
__global__ __launch_bounds__(64, 1) void k_gemm2(
    const float* __restrict__ Z, const float* __restrict__ p2s, const float* __restrict__ p2q,
    const float* __restrict__ go, const float* __restrict__ beo,
    const float* __restrict__ wo2, const float* __restrict__ bo2,
    float* __restrict__ out)
{
  __shared__ float sc2[128], sh2[128];
  const int ln = threadIdx.x, lo = ln & 31, hi = ln >> 5;
  for (int ch = ln; ch < 128; ch += 64){
    float s = 0.f, q = 0.f;
    for (int i = 0; i < 200; ++i){ s += p2s[i * 128 + ch]; q += p2q[i * 128 + ch]; }
    float mean = s * (1.f / NPIX);
    float var  = q * (1.f / NPIX) - mean * mean;
    float scale = go[ch] * rsqrtf(var + 1e-5f);
    sc2[ch] = scale; sh2[ch] = beo[ch] - mean * scale;
  }
  __syncthreads();
  const int p = blockIdx.x * 32 + lo;
  bf16x8 bfH[8];
  #pragma unroll
  for (int kk = 0; kk < 8; ++kk){
    int ob = kk * 16 + hi * 8;
    f4 z0 = *(const f4*)&Z[(size_t)p * 128 + ob];
    f4 z1 = *(const f4*)&Z[(size_t)p * 128 + ob + 4];
    f4 s0 = *(const f4*)&sc2[ob], s1 = *(const f4*)&sc2[ob + 4];
    f4 h0 = *(const f4*)&sh2[ob], h1 = *(const f4*)&sh2[ob + 4];
    union { bf16x8 v; u16 s16[8]; } u;
    #pragma unroll
    for (int e = 0; e < 4; ++e){
      u.s16[e]     = f2bf(fmaxf(z0[e] * s0[e] + h0[e], 0.f));
      u.s16[4 + e] = f2bf(fmaxf(z1[e] * s1[e] + h1[e], 0.f));
    }
    bfH[kk] = u.v;
  }
  f16v acc[4];
  #pragma unroll
  for (int c = 0; c < 4; ++c)
    #pragma unroll
    for (int r = 0; r < 16; ++r) acc[c][r] = 0.f;
  #pragma unroll
  for (int c = 0; c < 4; ++c){
    int o3r = c * 32 + lo;
    #pragma unroll
    for (int kk = 0; kk < 8; ++kk){
      const float* wp = wo2 + (size_t)o3r * 128 + kk * 16 + hi * 8;
      f4 w0 = *(const f4*)wp;
      f4 w1 = *(const f4*)(wp + 4);
      union { bf16x8 v; u16 s16[8]; } u;
      #pragma unroll
      for (int e = 0; e < 4; ++e){ u.s16[e] = f2bf(w0[e]); u.s16[4 + e] = f2bf(w1[e]); }
      acc[c] = __builtin_amdgcn_mfma_f32_32x32x16_bf16(u.v, bfH[kk], acc[c], 0, 0, 0);
    }
  }
  #pragma unroll
  for (int c = 0; c < 4; ++c){
    #pragma unroll
    for (int g = 0; g < 4; ++g){
      int o3 = c * 32 + g * 8 + hi * 4;
      f4 b4 = *(const f4*)&bo2[o3];
      #pragma unroll
      for (int e = 0; e < 4; ++e)
        out[(size_t)(o3 + e) * NPIX + p] = acc[c][g * 4 + e] + b4[e];
    }
  }
}

extern "C" void kernel_launch(void* const* d_in, const int* in_sizes, int n_in,
                              void* d_out, int out_size, void* d_ws, size_t ws_size,
                              hipStream_t stream)
{
  const float* query = (const float*)d_in[0];
  const float* key_  = (const float*)d_in[1];
  const float* value = (const float*)d_in[2];
  const float* pos   = (const float*)d_in[3];
  const float* wq = (const float*)d_in[4];  const float* bq = (const float*)d_in[5];
  const float* gq = (const float*)d_in[6];  const float* betaq = (const float*)d_in[7];
  const float* wk = (const float*)d_in[8];  const float* bk = (const float*)d_in[9];
  const float* gk = (const float*)d_in[10]; const float* betak = (const float*)d_in[11];
  const float* wv = (const float*)d_in[12]; const float* bv = (const float*)d_in[13];
  const float* gv = (const float*)d_in[14]; const float* betav = (const float*)d_in[15];
  const float* wo1 = (const float*)d_in[16]; const float* bo1 = (const float*)d_in[17];
  const float* go  = (const float*)d_in[18]; const float* betao = (const float*)d_in[19];
  const float* wo2 = (const float*)d_in[20]; const float* bo2 = (const float*)d_in[21];

  // adaptive K-split count based on available workspace (256 q-rows per block now)
  const size_t fixed = 8729600;          // q2,k2,v2t,rowsumq,psum,psq,Z,p2s,p2q
  auto need = [&](int j) -> size_t {
    size_t ml = (size_t)j * 51200;       // M + L
    size_t yy = (size_t)j * 3276800;     // Opart
    size_t ov = yy > 9830400 ? yy : (size_t)9830400;  // overlays Y
    return fixed + ml + ov;
  };
  int js = 5;
  if (ws_size >= need(10)) js = 10;      // 25*10 = 250 blocks = 1/CU, one round
  const int ktbase = 100 / js, ktrem = 100 % js;

  char* W = (char*)d_ws;
  size_t off = 0;
  auto alloc = [&](size_t n){ char* p = W + off; off += n; return p; };
  u16*  q2      = (u16*)alloc(1638400);
  u16*  k2      = (u16*)alloc(1638400);
  u16*  v2t     = (u16*)alloc(1638400);
  float* rowsumq= (float*)alloc(25600);
  float* psum   = (float*)alloc(153600);
  float* psq    = (float*)alloc(153600);
  float* Z      = (float*)alloc(3276800);
  float* p2s    = (float*)alloc(102400);
  float* p2q    = (float*)alloc(102400);
  float* Mbuf   = (float*)alloc((size_t)js * 25600);
  float* Lbuf   = (float*)alloc((size_t)js * 25600);
  float* Y      = (float*)(W + off);   // Yq,Yk,Yv (dead after k_norm)
  float* Opart  = (float*)(W + off);   // overlays Y
  float* Ocomb  = Opart;               // overlays Opart[0] (1:1 elementwise, race-free)

  k_proj <<<dim3(300), dim3(256), 0, stream>>>(query, key_, value, wq, bq, wk, bk, wv, bv, Y, psum, psq);
  k_norm <<<dim3(300), dim3(256), 0, stream>>>(Y, psum, psq, gq, betaq, gk, betak, gv, betav, q2, k2, v2t, rowsumq);
  k_flash<<<dim3(25 * js), dim3(512), 0, stream>>>(q2, k2, v2t, rowsumq, pos, Opart, Mbuf, Lbuf, js, ktbase, ktrem);
  k_comb <<<dim3(800), dim3(256), 0, stream>>>(Opart, Mbuf, Lbuf, Ocomb, js);
  k_gemm1<<<dim3(200), dim3(64), 0, stream>>>(Ocomb, wo1, bo1, Z, p2s, p2q);
  k_gemm2<<<dim3(200), dim3(64), 0, stream>>>(Z, p2s, p2q, go, betao, wo2, bo2, (float*)d_out);
}

// Round 5
// 120.455 us; speedup vs baseline: 1.3316x; 1.0851x over previous
//
#include <hip/hip_runtime.h>

#define NPIX 6400

typedef float f4 __attribute__((ext_vector_type(4)));
typedef float f16v __attribute__((ext_vector_type(16)));
typedef short bf16x8 __attribute__((ext_vector_type(8)));
typedef unsigned int u4 __attribute__((ext_vector_type(4)));
typedef unsigned short u16;
typedef unsigned int u32;

__device__ __forceinline__ u16 f2bf(float f){
  union { float f; u32 u; } v; v.f = f;
  u32 r = v.u + 0x7fffu + ((v.u >> 16) & 1u);
  return (u16)(r >> 16);
}

__device__ __forceinline__ float exp2_hw(float x){ return __builtin_amdgcn_exp2f(x); }

// ---------------- K1: projection GEMMs (fp32) + BN partial stats ----------------
__global__ __launch_bounds__(256, 1) void k_proj(
    const float* __restrict__ xq, const float* __restrict__ xk, const float* __restrict__ xv,
    const float* __restrict__ wq, const float* __restrict__ bq,
    const float* __restrict__ wk, const float* __restrict__ bk,
    const float* __restrict__ wv, const float* __restrict__ bv,
    float* __restrict__ Y, float* __restrict__ psum, float* __restrict__ psq)
{
  __shared__ __align__(16) float wT[64][132];
  __shared__ __align__(16) float xt[64][68];
  __shared__ __align__(16) float red[2][8][128];
  const int bid = blockIdx.x;
  const int proj = bid / 100, pt = bid % 100;
  const float* x = (proj == 0) ? xq : ((proj == 1) ? xk : xv);
  const float* w = (proj == 0) ? wq : ((proj == 1) ? wk : wv);
  const float* b = (proj == 0) ? bq : ((proj == 1) ? bk : bv);
  const int t = threadIdx.x;
  const int o0 = (t & 31) * 4, p0 = (t >> 5) * 8;
  float acc[4][8];
  #pragma unroll
  for (int i = 0; i < 4; ++i)
    #pragma unroll
    for (int j = 0; j < 8; ++j) acc[i][j] = 0.f;
  for (int cc = 0; cc < 2; ++cc){
    __syncthreads();
    for (int idx = t; idx < 2048; idx += 256){
      int o = idx >> 4, c4 = (idx & 15) * 4;
      f4 wv4 = *(const f4*)&w[o * 128 + cc * 64 + c4];
      wT[c4 + 0][o] = wv4[0]; wT[c4 + 1][o] = wv4[1];
      wT[c4 + 2][o] = wv4[2]; wT[c4 + 3][o] = wv4[3];
    }
    for (int idx = t; idx < 1024; idx += 256){
      int c = idx >> 4, p4 = (idx & 15) * 4;
      *(f4*)&xt[c][p4] = *(const f4*)&x[(cc * 64 + c) * NPIX + pt * 64 + p4];
    }
    __syncthreads();
    for (int c = 0; c < 64; ++c){
      f4 w4 = *(const f4*)&wT[c][o0];
      f4 x0 = *(const f4*)&xt[c][p0];
      f4 x1 = *(const f4*)&xt[c][p0 + 4];
      #pragma unroll
      for (int i = 0; i < 4; ++i){
        float wi = w4[i];
        #pragma unroll
        for (int j = 0; j < 4; ++j){ acc[i][j] += wi * x0[j]; acc[i][4 + j] += wi * x1[j]; }
      }
    }
  }
  f4 b4 = *(const f4*)&b[o0];
  #pragma unroll
  for (int i = 0; i < 4; ++i)
    #pragma unroll
    for (int j = 0; j < 8; ++j) acc[i][j] += b4[i];
  #pragma unroll
  for (int i = 0; i < 4; ++i){
    float s = 0.f, q = 0.f;
    #pragma unroll
    for (int j = 0; j < 8; ++j){ s += acc[i][j]; q += acc[i][j] * acc[i][j]; }
    red[0][t >> 5][o0 + i] = s;
    red[1][t >> 5][o0 + i] = q;
  }
  __syncthreads();
  if (t < 128){
    float s = 0.f, q = 0.f;
    #pragma unroll
    for (int g = 0; g < 8; ++g){ s += red[0][g][t]; q += red[1][g][t]; }
    psum[(proj * 100 + pt) * 128 + t] = s;
    psq [(proj * 100 + pt) * 128 + t] = q;
  }
  float* Yb = Y + (size_t)proj * NPIX * 128;
  if (proj < 2){
    #pragma unroll
    for (int j = 0; j < 8; ++j){
      f4 v; v[0] = acc[0][j]; v[1] = acc[1][j]; v[2] = acc[2][j]; v[3] = acc[3][j];
      *(f4*)&Yb[(size_t)(pt * 64 + p0 + j) * 128 + o0] = v;
    }
  } else {
    #pragma unroll
    for (int i = 0; i < 4; ++i){
      f4 v0, v1;
      #pragma unroll
      for (int j = 0; j < 4; ++j){ v0[j] = acc[i][j]; v1[j] = acc[i][4 + j]; }
      float* r = &Yb[(size_t)(o0 + i) * NPIX + pt * 64 + p0];
      *(f4*)r = v0; *(f4*)(r + 4) = v1;
    }
  }
}

// ---------------- K2: finalize BN affine + normalize+ReLU+bf16 cast ----------------
__global__ __launch_bounds__(256, 1) void k_norm(
    const float* __restrict__ Y, const float* __restrict__ psum, const float* __restrict__ psq,
    const float* __restrict__ gq, const float* __restrict__ beq,
    const float* __restrict__ gk, const float* __restrict__ bek,
    const float* __restrict__ gv, const float* __restrict__ bev,
    u16* __restrict__ q2, u16* __restrict__ k2, u16* __restrict__ v2t,
    float* __restrict__ rowsumq)
{
  __shared__ float sc[128], sh[128];
  const int bid = blockIdx.x, t = threadIdx.x;
  const int proj = bid / 100, pt = bid % 100;
  if (t < 128){
    float s = 0.f, q = 0.f;
    for (int i = 0; i < 100; ++i){
      s += psum[(proj * 100 + i) * 128 + t];
      q += psq [(proj * 100 + i) * 128 + t];
    }
    float mean = s * (1.f / NPIX);
    float var  = q * (1.f / NPIX) - mean * mean;
    const float* g  = (proj == 0) ? gq : ((proj == 1) ? gk : gv);
    const float* be = (proj == 0) ? beq : ((proj == 1) ? bek : bev);
    float scale = g[t] * rsqrtf(var + 1e-5f);
    sc[t] = scale; sh[t] = be[t] - mean * scale;
  }
  __syncthreads();
  const float* Yb = Y + (size_t)proj * NPIX * 128;
  if (proj < 2){
    int row = pt * 64 + (t >> 2), o0 = (t & 3) * 32;
    float rs = 0.f;
    u32 pkd[16];
    #pragma unroll
    for (int u = 0; u < 8; ++u){
      f4 y = *(const f4*)&Yb[(size_t)row * 128 + o0 + u * 4];
      #pragma unroll
      for (int e = 0; e < 4; ++e){
        int o = o0 + u * 4 + e;
        float v = fmaxf(y[e] * sc[o] + sh[o], 0.f);
        rs += v; y[e] = v;
      }
      pkd[u * 2]     = (u32)f2bf(y[0]) | ((u32)f2bf(y[1]) << 16);
      pkd[u * 2 + 1] = (u32)f2bf(y[2]) | ((u32)f2bf(y[3]) << 16);
    }
    u16* dst = (proj == 0) ? q2 : k2;
    u4* dp = (u4*)(dst + (size_t)row * 128 + o0);
    #pragma unroll
    for (int u = 0; u < 4; ++u){
      u4 v; v[0] = pkd[u*4]; v[1] = pkd[u*4+1]; v[2] = pkd[u*4+2]; v[3] = pkd[u*4+3];
      dp[u] = v;
    }
    if (proj == 0){
      rs += __shfl_xor(rs, 1);
      rs += __shfl_xor(rs, 2);
      if ((t & 3) == 0) rowsumq[row] = rs;
    }
  } else {
    int o = t >> 1, pc = pt * 64 + (t & 1) * 32;
    float scale = sc[o], shift = sh[o];
    u32 pkd[16];
    #pragma unroll
    for (int u = 0; u < 8; ++u){
      f4 y = *(const f4*)&Yb[(size_t)o * NPIX + pc + u * 4];
      #pragma unroll
      for (int e = 0; e < 4; ++e) y[e] = fmaxf(y[e] * scale + shift, 0.f);
      pkd[u * 2]     = (u32)f2bf(y[0]) | ((u32)f2bf(y[1]) << 16);
      pkd[u * 2 + 1] = (u32)f2bf(y[2]) | ((u32)f2bf(y[3]) << 16);
    }
    u4* dp = (u4*)(v2t + (size_t)o * NPIX + pc);
    #pragma unroll
    for (int u = 0; u < 4; ++u){
      u4 v; v[0] = pkd[u*4]; v[1] = pkd[u*4+1]; v[2] = pkd[u*4+2]; v[3] = pkd[u*4+3];
      dp[u] = v;
    }
  }
}

// ---------------- K3: flash attention, 512 threads, async-stage split (T14) ----------------
// grid 25*js: qb = bid/js (256 q-rows), jsi = bid%js. Wave owns 32 q-rows.
// Per tile: issue next tile's global loads -> compute -> barrier -> ds_write -> barrier.
__global__ __launch_bounds__(512, 2) void k_flash(
    const u16* __restrict__ q2, const u16* __restrict__ k2, const u16* __restrict__ v2t,
    const float* __restrict__ rowsumq, const float* __restrict__ pos,
    float* __restrict__ Opart, float* __restrict__ Mout, float* __restrict__ Lout,
    int js, int ktbase, int ktrem)
{
  __shared__ __align__(16) u16 Kt[64 * 128];
  __shared__ __align__(16) u16 Vt[128 * 64];
  __shared__ __align__(16) float posT[64];
  const int bid = blockIdx.x;
  const int qb = bid / js, jsi = bid % js;
  const int kt0 = jsi * ktbase + min(jsi, ktrem);
  const int nkt = ktbase + (jsi < ktrem ? 1 : 0);
  const int tid = threadIdx.x;
  const int ln = tid & 63, wid = tid >> 6;
  const int lo = ln & 31, hi = ln >> 5;
  const int qrow = qb * 256 + wid * 32 + lo;

  // staging register file + lambdas (T14: load early, write late)
  const int kc_j = tid >> 4, kc_c8 = tid & 15;   // K chunks: rows 0-31 and 32-63
  const int vc_d = tid >> 3, vc_c8 = tid & 7;    // V chunks: rows 0-63 and 64-127
  bf16x8 kreg0, kreg1, vreg0, vreg1; float posr = 0.f;
  auto stage_load = [&](int j0){
    kreg0 = *(const bf16x8*)(k2 + (size_t)(j0 + kc_j) * 128 + kc_c8 * 8);
    kreg1 = *(const bf16x8*)(k2 + (size_t)(j0 + kc_j + 32) * 128 + kc_c8 * 8);
    vreg0 = *(const bf16x8*)(v2t + (size_t)vc_d * NPIX + j0 + vc_c8 * 8);
    vreg1 = *(const bf16x8*)(v2t + (size_t)(vc_d + 64) * NPIX + j0 + vc_c8 * 8);
    if (tid < 64) posr = pos[j0 + tid];
  };
  auto stage_write = [&](){
    *(bf16x8*)((char*)Kt + kc_j * 256 + ((kc_c8 * 16) ^ ((kc_j & 15) << 4))) = kreg0;
    *(bf16x8*)((char*)Kt + (kc_j + 32) * 256 + ((kc_c8 * 16) ^ (((kc_j + 32) & 15) << 4))) = kreg1;
    *(bf16x8*)((char*)Vt + vc_d * 128 + ((vc_c8 * 16) ^ ((vc_d & 7) << 4))) = vreg0;
    *(bf16x8*)((char*)Vt + (vc_d + 64) * 128 + ((vc_c8 * 16) ^ (((vc_d + 64) & 7) << 4))) = vreg1;
    if (tid < 64) posT[tid] = posr;
  };

  bf16x8 qf[8];
  const u16* qp = q2 + (size_t)qrow * 128 + hi * 8;
  #pragma unroll
  for (int kk = 0; kk < 8; ++kk) qf[kk] = *(const bf16x8*)(qp + kk * 16);
  const float rsq_l2 = rowsumq[qrow] * 1.4426950408889634f;
  f16v accO[4];
  #pragma unroll
  for (int c = 0; c < 4; ++c)
    #pragma unroll
    for (int r = 0; r < 16; ++r) accO[c][r] = 0.f;
  float m = -1e30f, l = 0.f;
  const float qs_l2 = 0.12751700f; // 1/sqrt(128)/ln(2)

  stage_load(kt0 * 64);
  stage_write();
  __syncthreads();

  #pragma unroll 1
  for (int kt = 0; kt < nkt; ++kt){
    const bool more = (kt + 1 < nkt);
    if (more) stage_load((kt0 + kt + 1) * 64);   // in flight during compute

    f16v accS0, accS1;
    #pragma unroll
    for (int r = 0; r < 16; ++r){ accS0[r] = 0.f; accS1[r] = 0.f; }
    {
      const char* kb0 = (const char*)Kt + lo * 256;
      const char* kb1 = (const char*)Kt + (32 + lo) * 256;
      const int sw = (lo & 15) << 4;
      __builtin_amdgcn_s_setprio(1);
      #pragma unroll
      for (int kk = 0; kk < 8; ++kk){
        int bo = (kk * 32 + hi * 16) ^ sw;
        bf16x8 kf0 = *(const bf16x8*)(kb0 + bo);
        bf16x8 kf1 = *(const bf16x8*)(kb1 + bo);
        accS0 = __builtin_amdgcn_mfma_f32_32x32x16_bf16(kf0, qf[kk], accS0, 0, 0, 0);
        accS1 = __builtin_amdgcn_mfma_f32_32x32x16_bf16(kf1, qf[kk], accS1, 0, 0, 0);
      }
      __builtin_amdgcn_s_setprio(0);
    }
    float pv[32];
    float mx = -1e30f;
    #pragma unroll
    for (int jsb = 0; jsb < 2; ++jsb){
      #pragma unroll
      for (int g = 0; g < 4; ++g){
        f4 p4 = *(const f4*)&posT[jsb * 32 + g * 8 + hi * 4];
        #pragma unroll
        for (int e = 0; e < 4; ++e){
          float sv = (jsb ? accS1[g * 4 + e] : accS0[g * 4 + e]) * qs_l2 + rsq_l2 * p4[e];
          pv[jsb * 16 + g * 4 + e] = sv;
          mx = fmaxf(mx, sv);
        }
      }
    }
    mx = fmaxf(mx, __shfl_xor(mx, 32));
    if (!__all(mx - m <= 11.5f)){
      float mnew = fmaxf(m, mx);
      float corr = exp2_hw(m - mnew);
      m = mnew;
      l *= corr;
      #pragma unroll
      for (int c = 0; c < 4; ++c)
        #pragma unroll
        for (int r = 0; r < 16; ++r) accO[c][r] *= corr;
    }
    float ls = 0.f;
    u32 pk[16], pks[16];
    #pragma unroll
    for (int i = 0; i < 16; ++i){
      float e0 = exp2_hw(pv[2 * i]     - m);
      float e1 = exp2_hw(pv[2 * i + 1] - m);
      ls += e0 + e1;
      pk[i] = (u32)f2bf(e0) | ((u32)f2bf(e1) << 16);
    }
    ls += __shfl_xor(ls, 32);
    l += ls;
    #pragma unroll
    for (int i = 0; i < 16; ++i) pks[i] = __shfl_xor(pk[i], 32);
    #pragma unroll
    for (int w = 0; w < 4; ++w){
      const int b0 = (w >> 1) * 8 + (w & 1) * 4;
      union { bf16x8 v; u32 u[4]; } pf;
      pf.u[0] = hi ? pks[b0 + 2] : pk[b0];
      pf.u[1] = hi ? pks[b0 + 3] : pk[b0 + 1];
      pf.u[2] = hi ? pk[b0 + 2]  : pks[b0];
      pf.u[3] = hi ? pk[b0 + 3]  : pks[b0 + 1];
      __builtin_amdgcn_s_setprio(1);
      #pragma unroll
      for (int c = 0; c < 4; ++c){
        int d = c * 32 + lo;
        bf16x8 vf = *(const bf16x8*)((const char*)Vt + d * 128 + ((w * 32 + hi * 16) ^ ((d & 7) << 4)));
        accO[c] = __builtin_amdgcn_mfma_f32_32x32x16_bf16(vf, pf.v, accO[c], 0, 0, 0);
      }
      __builtin_amdgcn_s_setprio(0);
    }
    __syncthreads();                         // all waves done reading Kt/Vt/posT
    if (more){
      stage_write();                          // loads landed during compute
      __syncthreads();
    }
  }
  if (hi == 0){
    Mout[jsi * NPIX + qrow] = m;
    Lout[jsi * NPIX + qrow] = l;
  }
  float* Ob = Opart + ((size_t)jsi * NPIX + qrow) * 128;
  #pragma unroll
  for (int c = 0; c < 4; ++c){
    #pragma unroll
    for (int g = 0; g < 4; ++g){
      f4 v;
      #pragma unroll
      for (int e = 0; e < 4; ++e) v[e] = accO[c][g * 4 + e];
      *(f4*)&Ob[c * 32 + g * 8 + hi * 4] = v;
    }
  }
}

// ---------------- K3b: combine splits -> Ocomb (overlays Opart[0]) ----------------
// grid 400 x 256: thread -> (p, 8 channels). JS compile-time for full unroll (parallel loads).
template<int JS>
__global__ __launch_bounds__(256, 1) void k_comb(
    const float* __restrict__ Opart, const float* __restrict__ Mbuf, const float* __restrict__ Lbuf,
    float* __restrict__ Ocomb)
{
  const int idx = blockIdx.x * 256 + threadIdx.x;
  const int p = idx >> 4, c8 = (idx & 15) * 8;
  float mv[JS];
  #pragma unroll
  for (int s = 0; s < JS; ++s) mv[s] = Mbuf[s * NPIX + p];
  float mmax = -1e30f;
  #pragma unroll
  for (int s = 0; s < JS; ++s) mmax = fmaxf(mmax, mv[s]);
  float den = 0.f;
  f4 acc0 = {0.f,0.f,0.f,0.f}, acc1 = {0.f,0.f,0.f,0.f};
  #pragma unroll
  for (int s = 0; s < JS; ++s){
    float w = exp2_hw(mv[s] - mmax);
    den += w * Lbuf[s * NPIX + p];
    const float* op = &Opart[((size_t)s * NPIX + p) * 128 + c8];
    f4 a = *(const f4*)op, b = *(const f4*)(op + 4);
    acc0 += a * w; acc1 += b * w;
  }
  float inv = 1.f / den;
  float* dst = &Ocomb[(size_t)p * 128 + c8];
  *(f4*)dst = acc0 * inv;
  *(f4*)(dst + 4) = acc1 * inv;
}

// ---------------- K4: Z = Ocomb@wo1^T + bo1 (4 waves, wo1 in LDS) + BN2 partials ----------
__global__ __launch_bounds__(256, 1) void k_out1(
    const float* __restrict__ Ocomb, const float* __restrict__ wo1, const float* __restrict__ bo1,
    float* __restrict__ Z, float* __restrict__ p2s, float* __restrict__ p2q)
{
  __shared__ __align__(16) u16 wl[128 * 128];
  const int tid = threadIdx.x;
  {
    const int o = tid >> 1, h = tid & 1;
    const float* wp = wo1 + o * 128 + h * 64;
    char* dst = (char*)wl + o * 256;
    const int sw = (o & 15) << 4;
    #pragma unroll
    for (int u = 0; u < 8; ++u){
      f4 a = *(const f4*)(wp + u * 8);
      f4 b = *(const f4*)(wp + u * 8 + 4);
      union { bf16x8 v; u16 s[8]; } cc;
      #pragma unroll
      for (int e = 0; e < 4; ++e){ cc.s[e] = f2bf(a[e]); cc.s[4 + e] = f2bf(b[e]); }
      *(bf16x8*)(dst + ((h * 128 + u * 16) ^ sw)) = cc.v;
    }
  }
  __syncthreads();
  const int ln = tid & 63, wid = tid >> 6, lo = ln & 31, hi = ln >> 5;
  const int p = blockIdx.x * 128 + wid * 32 + lo;
  bf16x8 bfr[8];
  #pragma unroll
  for (int kk = 0; kk < 8; ++kk){
    const float* op = Ocomb + (size_t)p * 128 + kk * 16 + hi * 8;
    f4 a0 = *(const f4*)op, a1 = *(const f4*)(op + 4);
    union { bf16x8 v; u16 s[8]; } u;
    #pragma unroll
    for (int e = 0; e < 4; ++e){ u.s[e] = f2bf(a0[e]); u.s[4 + e] = f2bf(a1[e]); }
    bfr[kk] = u.v;
  }
  f16v acc[4];
  #pragma unroll
  for (int c = 0; c < 4; ++c)
    #pragma unroll
    for (int r = 0; r < 16; ++r) acc[c][r] = 0.f;
  #pragma unroll
  for (int c = 0; c < 4; ++c){
    const int o = c * 32 + lo;
    const char* wrow = (const char*)wl + o * 256;
    const int sw = (o & 15) << 4;
    #pragma unroll
    for (int kk = 0; kk < 8; ++kk){
      bf16x8 wf = *(const bf16x8*)(wrow + ((kk * 32 + hi * 16) ^ sw));
      acc[c] = __builtin_amdgcn_mfma_f32_32x32x16_bf16(wf, bfr[kk], acc[c], 0, 0, 0);
    }
  }
  #pragma unroll
  for (int c = 0; c < 4; ++c){
    #pragma unroll
    for (int g = 0; g < 4; ++g){
      const int o2 = c * 32 + g * 8 + hi * 4;
      f4 b4 = *(const f4*)&bo1[o2];
      f4 zv;
      #pragma unroll
      for (int e = 0; e < 4; ++e) zv[e] = acc[c][g * 4 + e] + b4[e];
      *(f4*)&Z[(size_t)p * 128 + o2] = zv;
      #pragma unroll
      for (int e = 0; e < 4; ++e){
        float sv = zv[e], qv = zv[e] * zv[e];
        #pragma unroll
        for (int msk = 1; msk < 32; msk <<= 1){ sv += __shfl_xor(sv, msk); qv += __shfl_xor(qv, msk); }
        if (lo == 0){
          p2s[(blockIdx.x * 4 + wid) * 128 + o2 + e] = sv;
          p2q[(blockIdx.x * 4 + wid) * 128 + o2 + e] = qv;
        }
      }
    }
  }
}

// ---------------- K5: finalize BN2 + H=relu(affine(Z)) + out = wo2@H + bo2 ----------
__global__ __launch_bounds__(256, 1) void k_out2(
    const float* __restrict__ Z, const float* __restrict__ p2s, const float* __restrict__ p2q,
    const float* __restrict__ go, const float* __restrict__ beo,
    const float* __restrict__ wo2, const float* __restrict__ bo2,
    float* __restrict__ out)
{
  __shared__ __align__(16) u16 wl[128 * 128];
  __shared__ float sc2[128], sh2[128];
  const int tid = threadIdx.x;
  if (tid < 128){
    float s = 0.f, q = 0.f;
    for (int i = 0; i < 200; ++i){ s += p2s[i * 128 + tid]; q += p2q[i * 128 + tid]; }
    float mean = s * (1.f / NPIX);
    float var  = q * (1.f / NPIX) - mean * mean;
    float scale = go[tid] * rsqrtf(var + 1e-5f);
    sc2[tid] = scale; sh2[tid] = beo[tid] - mean * scale;
  }
  {
    const int o = tid >> 1, h = tid & 1;
    const float* wp = wo2 + o * 128 + h * 64;
    char* dst = (char*)wl + o * 256;
    const int sw = (o & 15) << 4;
    #pragma unroll
    for (int u = 0; u < 8; ++u){
      f4 a = *(const f4*)(wp + u * 8);
      f4 b = *(const f4*)(wp + u * 8 + 4);
      union { bf16x8 v; u16 s[8]; } cc;
      #pragma unroll
      for (int e = 0; e < 4; ++e){ cc.s[e] = f2bf(a[e]); cc.s[4 + e] = f2bf(b[e]); }
      *(bf16x8*)(dst + ((h * 128 + u * 16) ^ sw)) = cc.v;
    }
  }
  __syncthreads();
  const int ln = tid & 63, wid = tid >> 6, lo = ln & 31, hi = ln >> 5;
  const int p = blockIdx.x * 128 + wid * 32 + lo;
  bf16x8 bfH[8];
  #pragma unroll
  for (int kk = 0; kk < 8; ++kk){
    int ob = kk * 16 + hi * 8;
    f4 z0 = *(const f4*)&Z[(size_t)p * 128 + ob];
    f4 z1 = *(const f4*)&Z[(size_t)p * 128 + ob + 4];
    f4 s0 = *(const f4*)&sc2[ob], s1 = *(const f4*)&sc2[ob + 4];
    f4 h0 = *(const f4*)&sh2[ob], h1 = *(const f4*)&sh2[ob + 4];
    union { bf16x8 v; u16 s[8]; } u;
    #pragma unroll
    for (int e = 0; e < 4; ++e){
      u.s[e]     = f2bf(fmaxf(z0[e] * s0[e] + h0[e], 0.f));
      u.s[4 + e] = f2bf(fmaxf(z1[e] * s1[e] + h1[e], 0.f));
    }
    bfH[kk] = u.v;
  }
  f16v acc[4];
  #pragma unroll
  for (int c = 0; c < 4; ++c)
    #pragma unroll
    for (int r = 0; r < 16; ++r) acc[c][r] = 0.f;
  #pragma unroll
  for (int c = 0; c < 4; ++c){
    const int o = c * 32 + lo;
    const char* wrow = (const char*)wl + o * 256;
    const int sw = (o & 15) << 4;
    #pragma unroll
    for (int kk = 0; kk < 8; ++kk){
      bf16x8 wf = *(const bf16x8*)(wrow + ((kk * 32 + hi * 16) ^ sw));
      acc[c] = __builtin_amdgcn_mfma_f32_32x32x16_bf16(wf, bfH[kk], acc[c], 0, 0, 0);
    }
  }
  #pragma unroll
  for (int c = 0; c < 4; ++c){
    #pragma unroll
    for (int g = 0; g < 4; ++g){
      const int o3 = c * 32 + g * 8 + hi * 4;
      f4 b4 = *(const f4*)&bo2[o3];
      #pragma unroll
      for (int e = 0; e < 4; ++e)
        out[(size_t)(o3 + e) * NPIX + p] = acc[c][g * 4 + e] + b4[e];
    }
  }
}

extern "C" void kernel_launch(void* const* d_in, const int* in_sizes, int n_in,
                              void* d_out, int out_size, void* d_ws, size_t ws_size,
                              hipStream_t stream)
{
  const float* query = (const float*)d_in[0];
  const float* key_  = (const float*)d_in[1];
  const float* value = (const float*)d_in[2];
  const float* pos   = (const float*)d_in[3];
  const float* wq = (const float*)d_in[4];  const float* bq = (const float*)d_in[5];
  const float* gq = (const float*)d_in[6];  const float* betaq = (const float*)d_in[7];
  const float* wk = (const float*)d_in[8];  const float* bk = (const float*)d_in[9];
  const float* gk = (const float*)d_in[10]; const float* betak = (const float*)d_in[11];
  const float* wv = (const float*)d_in[12]; const float* bv = (const float*)d_in[13];
  const float* gv = (const float*)d_in[14]; const float* betav = (const float*)d_in[15];
  const float* wo1 = (const float*)d_in[16]; const float* bo1 = (const float*)d_in[17];
  const float* go  = (const float*)d_in[18]; const float* betao = (const float*)d_in[19];
  const float* wo2 = (const float*)d_in[20]; const float* bo2 = (const float*)d_in[21];

  // adaptive K-split count based on available workspace (256 q-rows per flash block)
  const size_t fixed = 8729600;          // q2,k2,v2t,rowsumq,psum,psq,Z,p2s,p2q
  auto need = [&](int j) -> size_t {
    size_t ml = (size_t)j * 51200;       // M + L
    size_t yy = (size_t)j * 3276800;     // Opart
    size_t ov = yy > 9830400 ? yy : (size_t)9830400;  // overlays Y
    return fixed + ml + ov;
  };
  int js = 5;
  if (ws_size >= need(10)) js = 10;      // 25*10 = 250 blocks = 1/CU, one round
  const int ktbase = 100 / js, ktrem = 100 % js;

  char* W = (char*)d_ws;
  size_t off = 0;
  auto alloc = [&](size_t n){ char* p = W + off; off += n; return p; };
  u16*  q2      = (u16*)alloc(1638400);
  u16*  k2      = (u16*)alloc(1638400);
  u16*  v2t     = (u16*)alloc(1638400);
  float* rowsumq= (float*)alloc(25600);
  float* psum   = (float*)alloc(153600);
  float* psq    = (float*)alloc(153600);
  float* Z      = (float*)alloc(3276800);
  float* p2s    = (float*)alloc(102400);
  float* p2q    = (float*)alloc(102400);
  float* Mbuf   = (float*)alloc((size_t)js * 25600);
  float* Lbuf   = (float*)alloc((size_t)js * 25600);
  float* Y      = (float*)(W + off);   // Yq,Yk,Yv (dead after k_norm)
  float* Opart  = (float*)(W + off);   // overlays Y
  float* Ocomb  = Opart;               // overlays Opart[0] (1:1 elementwise, race-free)

  k_proj <<<dim3(300), dim3(256), 0, stream>>>(query, key_, value, wq, bq, wk, bk, wv, bv, Y, psum, psq);
  k_norm <<<dim3(300), dim3(256), 0, stream>>>(Y, psum, psq, gq, betaq, gk, betak, gv, betav, q2, k2, v2t, rowsumq);
  k_flash<<<dim3(25 * js), dim3(512), 0, stream>>>(q2, k2, v2t, rowsumq, pos, Opart, Mbuf, Lbuf, js, ktbase, ktrem);
  if (js == 10) k_comb<10><<<dim3(400), dim3(256), 0, stream>>>(Opart, Mbuf, Lbuf, Ocomb);
  else          k_comb<5> <<<dim3(400), dim3(256), 0, stream>>>(Opart, Mbuf, Lbuf, Ocomb);
  k_out1 <<<dim3(50), dim3(256), 0, stream>>>(Ocomb, wo1, bo1, Z, p2s, p2q);
  k_out2 <<<dim3(50), dim3(256), 0, stream>>>(Z, p2s, p2q, go, betao, wo2, bo2, (float*)d_out);
}